// Round 5
// baseline (1021.909 us; speedup 1.0000x reference)
//
#include <hip/hip_runtime.h>
#include <hip/hip_bf16.h>
#include <stdint.h>
#include <stddef.h>

#define TT 128
#define BB 16
#define VV 50000
#define DD 300
#define HH 256
#define WW 5
#define MM (TT*BB)      // 2048
#define NPAD 50176      // padded N for W2^T (784*64)
#define K1 3072         // padded GEMM1 K (3000 -> 192 ksteps)
#define KC 192          // GEMM1 k-chunk per block (12 ksteps)

typedef __bf16 bf16x8 __attribute__((ext_vector_type(8)));
typedef float  f32x16 __attribute__((ext_vector_type(16)));

typedef const __attribute__((address_space(1))) uint32_t as1_u32;
typedef __attribute__((address_space(3))) uint32_t       as3_u32;

static __device__ __forceinline__ ushort rne_bf16(float v) {
  uint32_t u = __builtin_bit_cast(uint32_t, v);
  u += 0x7fffu + ((u >> 16) & 1u);
  return (ushort)(u >> 16);
}
static __device__ __forceinline__ float bf16_to_f(ushort h) {
  return __builtin_bit_cast(float, (uint32_t)h << 16);
}

// ---------------------------------------------------------------------------
// kzero: zero the GEMM1 accumulator (ws is poisoned 0xAA).
// ---------------------------------------------------------------------------
__global__ void kzero(float* __restrict__ p) {
  int i = blockIdx.x * 256 + threadIdx.x;   // 131072 quads exactly
  reinterpret_cast<float4*>(p)[i] = make_float4(0.f, 0.f, 0.f, 0.f);
}

// ---------------------------------------------------------------------------
// kW1t: W1 [3000][256] f32 -> W1t hi/lo [256][3072] bf16. 12 blocks.
// float4 reads (1KB per row visit), register transpose, 16B granule stores.
// ---------------------------------------------------------------------------
__global__ __launch_bounds__(256, 1)
void kW1t(const float* __restrict__ W1, ushort* __restrict__ tHi,
          ushort* __restrict__ tLo) {
  const int tid = threadIdx.x;
  const int lane = tid & 63;
  const int w = tid >> 6;
  const int k0 = blockIdx.x * 256;
  for (int pass = 0; pass < 8; ++pass) {
    const int gl = w + pass * 4;         // granule 0..31 within chunk
    float fv[8][4];
#pragma unroll
    for (int e = 0; e < 8; ++e) {
      int k = k0 + gl * 8 + e;
      float4 f = make_float4(0.f, 0.f, 0.f, 0.f);
      if (k < 2 * WW * DD)
        f = *reinterpret_cast<const float4*>(&W1[(size_t)k * HH + lane * 4]);
      fv[e][0] = f.x; fv[e][1] = f.y; fv[e][2] = f.z; fv[e][3] = f.w;
    }
#pragma unroll
    for (int jj = 0; jj < 4; ++jj) {
      int j = lane * 4 + jj;
      alignas(16) ushort h8[8], l8[8];
#pragma unroll
      for (int e = 0; e < 8; ++e) {
        float v = fv[e][jj];
        ushort hb = rne_bf16(v);
        h8[e] = hb;
        l8[e] = rne_bf16(v - bf16_to_f(hb));
      }
      size_t o = (size_t)j * K1 + k0 + gl * 8;
      *reinterpret_cast<uint4*>(tHi + o) = *reinterpret_cast<const uint4*>(h8);
      *reinterpret_cast<uint4*>(tLo + o) = *reinterpret_cast<const uint4*>(l8);
    }
  }
}

// ---------------------------------------------------------------------------
// k2: W2 [256][50000] f32 -> W2t hi/lo [NPAD][256] bf16. 196 blocks.
// n-tile 256: float4 reads = 1KB contiguous per DRAM row visit (fixes page
// thrash of 256B strided reads). Register transpose, 16B granule stores
// (consecutive granules of a row come from sibling waves -> L2 coalesces).
// ---------------------------------------------------------------------------
__global__ __launch_bounds__(256, 1)
void k2_w2t(const float* __restrict__ W2, ushort* __restrict__ tHi,
            ushort* __restrict__ tLo) {
  const int tid = threadIdx.x;
  const int lane = tid & 63;
  const int w = tid >> 6;
  const int n0 = blockIdx.x * 256;
  const bool safe = (n0 + 256 <= VV);
  for (int pass = 0; pass < 8; ++pass) {
    const int g = w + pass * 4;          // granule 0..31 (k = g*8..g*8+7)
    float fv[8][4];
#pragma unroll
    for (int e = 0; e < 8; ++e) {
      int k = g * 8 + e;
      if (safe) {
        float4 f = *reinterpret_cast<const float4*>(&W2[(size_t)k * VV + n0 + lane * 4]);
        fv[e][0] = f.x; fv[e][1] = f.y; fv[e][2] = f.z; fv[e][3] = f.w;
      } else {
#pragma unroll
        for (int jj = 0; jj < 4; ++jj) {
          int n = n0 + lane * 4 + jj;
          fv[e][jj] = (n < VV) ? W2[(size_t)k * VV + n] : 0.f;
        }
      }
    }
#pragma unroll
    for (int jj = 0; jj < 4; ++jj) {
      int n = n0 + lane * 4 + jj;
      alignas(16) ushort h8[8], l8[8];
#pragma unroll
      for (int e = 0; e < 8; ++e) {
        float v = fv[e][jj];
        ushort hb = rne_bf16(v);
        h8[e] = hb;
        l8[e] = rne_bf16(v - bf16_to_f(hb));
      }
      size_t o = (size_t)n * 256 + g * 8;
      *reinterpret_cast<uint4*>(tHi + o) = *reinterpret_cast<const uint4*>(h8);
      *reinterpret_cast<uint4*>(tLo + o) = *reinterpret_cast<const uint4*>(l8);
    }
  }
}

// ---------------------------------------------------------------------------
// k1b: GEMM1 split-K via MFMA. Grid 512 = 32 m-blocks x 16 k-chunks.
// Per block: gather A-chunk [64 m][192 k] (embeddings, token 0 padding)
// straight into LDS as bf16 hi/lo, then 12 ksteps of 32x32x16 MFMA
// against W1t (L2-resident), atomicAdd fp32 partials into hacc.
// LDS 50KB -> 3 blocks/CU.
// ---------------------------------------------------------------------------
__global__ __launch_bounds__(256, 1)
void k1b_gemm1(const int* __restrict__ text, const float* __restrict__ Ef,
               const float* __restrict__ Eu, const ushort* __restrict__ w1tHi,
               const ushort* __restrict__ w1tLo, float* __restrict__ hacc) {
  __shared__ ushort aHi[64 * 200];   // row pad 200 ushorts (400B, 16B-aligned)
  __shared__ ushort aLo[64 * 200];
  const int tid = threadIdx.x;
  const int mblk = blockIdx.x & 31;
  const int kc   = blockIdx.x >> 5;
  const int m0 = mblk * 64;
  const int k0 = kc * KC;

  for (int f = tid; f < 64 * KC; f += 256) {
    int r = f / KC;
    int kl = f - r * KC;
    int m = m0 + r;
    int t = m >> 4, b = m & 15;
    int k = k0 + kl;
    float v = 0.f;
    if (k < 2 * WW * DD) {
      int wdx = k / (2 * DD);
      int rem = k - wdx * (2 * DD);
      int tw = t - WW + wdx;
      int tok = (tw >= 0) ? text[tw * BB + b] : 0;
      bool upd = (rem >= DD);
      int d = upd ? rem - DD : rem;
      const float* tab = upd ? Eu : Ef;
      v = tab[(size_t)tok * DD + d];
    }
    ushort hb = rne_bf16(v);
    aHi[r * 200 + kl] = hb;
    aLo[r * 200 + kl] = rne_bf16(v - bf16_to_f(hb));
  }
  __syncthreads();

  const int lane = tid & 63;
  const int wid  = tid >> 6;
  const int wm = wid & 1;          // m-wave (0..1), 32 rows each
  const int wn = wid >> 1;         // n-wave (0..1), 128 cols each
  const int arow = lane & 31;
  const int kg = lane >> 5;

  f32x16 acc[4] = {};
  const int arbase = (wm * 32 + arow) * 200 + kg * 8;
#pragma unroll
  for (int ks = 0; ks < KC / 16; ++ks) {
    bf16x8 aH = *reinterpret_cast<const bf16x8*>(&aHi[arbase + ks * 16]);
    bf16x8 aL = *reinterpret_cast<const bf16x8*>(&aLo[arbase + ks * 16]);
#pragma unroll
    for (int fn = 0; fn < 4; ++fn) {
      int col = wn * 128 + fn * 32 + arow;
      size_t bo = (size_t)col * K1 + k0 + ks * 16 + kg * 8;
      bf16x8 bH = *reinterpret_cast<const bf16x8*>(w1tHi + bo);
      bf16x8 bL = *reinterpret_cast<const bf16x8*>(w1tLo + bo);
      acc[fn] = __builtin_amdgcn_mfma_f32_32x32x16_bf16(aH, bH, acc[fn], 0, 0, 0);
      acc[fn] = __builtin_amdgcn_mfma_f32_32x32x16_bf16(aH, bL, acc[fn], 0, 0, 0);
      acc[fn] = __builtin_amdgcn_mfma_f32_32x32x16_bf16(aL, bH, acc[fn], 0, 0, 0);
    }
  }
#pragma unroll
  for (int fn = 0; fn < 4; ++fn) {
    int col = wn * 128 + fn * 32 + arow;
#pragma unroll
    for (int rg = 0; rg < 16; ++rg) {
      int row = m0 + wm * 32 + (rg & 3) + 8 * (rg >> 2) + 4 * kg;
      atomicAdd(&hacc[row * HH + col], acc[fn][rg]);
    }
  }
}

// ---------------------------------------------------------------------------
// k1c: h = tanh(hacc + b1) -> bf16 hi/lo. 512 blocks x 256 thr, float4.
// ---------------------------------------------------------------------------
__global__ void k1c_act(const float* __restrict__ hacc, const float* __restrict__ b1,
                        ushort* __restrict__ hHi, ushort* __restrict__ hLo) {
  int i = blockIdx.x * 256 + threadIdx.x;   // quad index, 131072 exactly
  int m = i >> 6;
  int j4 = (i & 63) * 4;
  float4 a = *reinterpret_cast<const float4*>(&hacc[(size_t)m * HH + j4]);
  float4 bb = *reinterpret_cast<const float4*>(&b1[j4]);
  float th[4] = {tanhf(a.x + bb.x), tanhf(a.y + bb.y),
                 tanhf(a.z + bb.z), tanhf(a.w + bb.w)};
  ushort h4[4], l4[4];
#pragma unroll
  for (int q = 0; q < 4; ++q) {
    ushort hb = rne_bf16(th[q]);
    h4[q] = hb;
    l4[q] = rne_bf16(th[q] - bf16_to_f(hb));
  }
  *reinterpret_cast<ushort4*>(&hHi[(size_t)m * HH + j4]) = *reinterpret_cast<const ushort4*>(h4);
  *reinterpret_cast<ushort4*>(&hLo[(size_t)m * HH + j4]) = *reinterpret_cast<const ushort4*>(l4);
}

// ---------------------------------------------------------------------------
// kE: logits = h @ W2 + b2, split-bf16 3-term MFMA.
// BM=256 x BN=64, 8 waves (4m x 2n), full K=256 in 64KB LDS -> 2 blocks/CU.
// Ping-pong register prefetch of next-kstep A (global) + B (LDS) fragments.
// XCD-grouped grid: 6272 = 98 grp x 8 m x 8 xcd; all 8 m-blocks of an
// n-slice share one XCD L2 -> W2t fetched from HBM once.
// ---------------------------------------------------------------------------
__global__ __launch_bounds__(512, 4)
void kE_gemm2(const ushort* __restrict__ hHi, const ushort* __restrict__ hLo,
              const ushort* __restrict__ bHiG, const ushort* __restrict__ bLoG,
              const float* __restrict__ b2, float* __restrict__ out) {
  __shared__ ushort Bsh[2][64 * 256];   // 64 KB
  const int tid = threadIdx.x;
  const int lane = tid & 63;
  const int wid = tid >> 6;
  const int wm = wid & 3;
  const int wn = wid >> 2;
  const int bid = blockIdx.x;
  const int n_idx = (bid >> 6) * 8 + (bid & 7);
  const int m_idx = (bid >> 3) & 7;
  const int m0 = m_idx * 256;
  const int n0 = n_idx * 64;

  {  // stage B hi/lo (XOR-swizzled source granule, linear LDS dest)
    const int r = tid >> 5;
    const int p = tid & 31;
    const int wave_off = wid << 10;
    char* baseH = (char*)(&Bsh[0][0]);
    char* baseL = (char*)(&Bsh[1][0]);
#pragma unroll
    for (int i = 0; i < 4; ++i) {
      int row = (i << 4) + r;
      int g = p ^ (row & 31);
      size_t soff = (((size_t)(n0 + row)) << 8) + ((size_t)g << 3);
      __builtin_amdgcn_global_load_lds((as1_u32*)(bHiG + soff),
                                       (as3_u32*)(baseH + (i << 13) + wave_off), 16, 0, 0);
      __builtin_amdgcn_global_load_lds((as1_u32*)(bLoG + soff),
                                       (as3_u32*)(baseL + (i << 13) + wave_off), 16, 0, 0);
    }
  }

  const int arow = lane & 31;
  const int kg = lane >> 5;
  const size_t aoff = (size_t)(m0 + wm * 64 + arow) * 256 + kg * 8;
  const ushort* aHb = hHi + aoff;
  const ushort* aLb = hLo + aoff;
  const int brow = wn * 32 + arow;           // 0..63
  const ushort* bHs = &Bsh[0][brow * 256];
  const ushort* bLs = &Bsh[1][brow * 256];

  bf16x8 aH[2][2], aL[2][2], bH[2], bL[2];
#pragma unroll
  for (int fm = 0; fm < 2; ++fm) {           // prologue A(ks=0) before barrier
    aH[0][fm] = *reinterpret_cast<const bf16x8*>(aHb + fm * 32 * 256);
    aL[0][fm] = *reinterpret_cast<const bf16x8*>(aLb + fm * 32 * 256);
  }
  __syncthreads();
  {
    int g0 = (kg ^ arow) * 8;                // ks=0 granule
    bH[0] = *reinterpret_cast<const bf16x8*>(bHs + g0);
    bL[0] = *reinterpret_cast<const bf16x8*>(bLs + g0);
  }

  f32x16 acc[2] = {};
#pragma unroll
  for (int ks = 0; ks < 16; ++ks) {
    const int cur = ks & 1, nxt = cur ^ 1;
    if (ks < 15) {
      const int kn = ks + 1;
#pragma unroll
      for (int fm = 0; fm < 2; ++fm) {
        aH[nxt][fm] = *reinterpret_cast<const bf16x8*>(aHb + fm * 32 * 256 + kn * 16);
        aL[nxt][fm] = *reinterpret_cast<const bf16x8*>(aLb + fm * 32 * 256 + kn * 16);
      }
      int g = ((kn * 2 + kg) ^ arow) * 8;
      bH[nxt] = *reinterpret_cast<const bf16x8*>(bHs + g);
      bL[nxt] = *reinterpret_cast<const bf16x8*>(bLs + g);
    }
#pragma unroll
    for (int fm = 0; fm < 2; ++fm) {
      acc[fm] = __builtin_amdgcn_mfma_f32_32x32x16_bf16(aH[cur][fm], bH[cur], acc[fm], 0, 0, 0);
      acc[fm] = __builtin_amdgcn_mfma_f32_32x32x16_bf16(aH[cur][fm], bL[cur], acc[fm], 0, 0, 0);
      acc[fm] = __builtin_amdgcn_mfma_f32_32x32x16_bf16(aL[cur][fm], bH[cur], acc[fm], 0, 0, 0);
    }
  }

  const int col = n0 + brow;
  const bool ok = col < VV;
  const float bias = ok ? b2[col] : 0.f;
#pragma unroll
  for (int fm = 0; fm < 2; ++fm) {
    int mbase = m0 + wm * 64 + fm * 32 + 4 * kg;
#pragma unroll
    for (int rg = 0; rg < 16; ++rg) {
      int rr = (rg & 3) + 8 * (rg >> 2);
      if (ok) out[(size_t)(mbase + rr) * VV + col] = acc[fm][rg] + bias;
    }
  }
}

// ---------------------------------------------------------------------------
extern "C" void kernel_launch(void* const* d_in, const int* in_sizes, int n_in,
                              void* d_out, int out_size, void* d_ws, size_t ws_size,
                              hipStream_t stream) {
  (void)in_sizes; (void)n_in; (void)out_size; (void)ws_size;
  const int*   text = (const int*)d_in[0];
  const float* Ef   = (const float*)d_in[1];
  const float* Eu   = (const float*)d_in[2];
  const float* W1   = (const float*)d_in[3];
  const float* b1   = (const float*)d_in[4];
  const float* W2   = (const float*)d_in[5];
  const float* b2   = (const float*)d_in[6];
  float* out = (float*)d_out;

  // workspace layout (~58.7 MB)
  ushort* w2tHi = (ushort*)d_ws;
  ushort* w2tLo = w2tHi + (size_t)NPAD * 256;
  ushort* w1tHi = w2tLo + (size_t)NPAD * 256;
  ushort* w1tLo = w1tHi + (size_t)HH * K1;
  float*  hacc  = (float*)(w1tLo + (size_t)HH * K1);
  ushort* hHi   = (ushort*)(hacc + (size_t)MM * HH);
  ushort* hLo   = hHi + (size_t)MM * HH;

  hipLaunchKernelGGL(kzero, dim3(512), dim3(256), 0, stream, hacc);
  hipLaunchKernelGGL(kW1t, dim3(K1 / 256), dim3(256), 0, stream, W1, w1tHi, w1tLo);
  hipLaunchKernelGGL(k2_w2t, dim3(NPAD / 256), dim3(256), 0, stream, W2, w2tHi, w2tLo);
  hipLaunchKernelGGL(k1b_gemm1, dim3(512), dim3(256), 0, stream,
                     text, Ef, Eu, w1tHi, w1tLo, hacc);
  hipLaunchKernelGGL(k1c_act, dim3(512), dim3(256), 0, stream, hacc, b1, hHi, hLo);
  hipLaunchKernelGGL(kE_gemm2, dim3(8 * 784), dim3(512), 0, stream,
                     hHi, hLo, w2tHi, w2tLo, b2, out);
}

// Round 7
// 938.291 us; speedup vs baseline: 1.0891x; 1.0891x over previous
//
#include <hip/hip_runtime.h>
#include <hip/hip_bf16.h>
#include <stdint.h>
#include <stddef.h>

#define VV 50000
#define DD 300
#define HH 256
#define WW 5
#define MM 2048         // T*B
#define NPAD 50176      // 392*128
#define KSG1 192        // GEMM1 k-steps (3072/16)

typedef __bf16 bf16x8 __attribute__((ext_vector_type(8)));
typedef float  f32x16 __attribute__((ext_vector_type(16)));

typedef const __attribute__((address_space(1))) uint32_t as1_u32;
typedef __attribute__((address_space(3))) uint32_t       as3_u32;

static __device__ __forceinline__ ushort rne_bf16(float v) {
  uint32_t u = __builtin_bit_cast(uint32_t, v);
  u += 0x7fffu + ((u >> 16) & 1u);
  return (ushort)(u >> 16);
}
static __device__ __forceinline__ float bf16_to_f(ushort h) {
  return __builtin_bit_cast(float, (uint32_t)h << 16);
}

// ---------------------------------------------------------------------------
// kW1f: W1 [3000][256] f32 -> frag-ordered hi/lo: [(ksg*8+jgrp)][lane][8].
// Wave-task (ksg,jgrp): lane (jl=l&31, kg=l>>5) reads 8 k-rows, writes 16B.
// ---------------------------------------------------------------------------
__global__ __launch_bounds__(256, 1)
void kW1f(const float* __restrict__ W1, ushort* __restrict__ fHi,
          ushort* __restrict__ fLo) {
  const int tid = threadIdx.x;
  const int lane = tid & 63;
  const int task = blockIdx.x * 4 + (tid >> 6);   // 0..1535
  const int ksg = task >> 3;
  const int jgrp = task & 7;
  const int jl = lane & 31, kg = lane >> 5;
  const int j = jgrp * 32 + jl;
  alignas(16) ushort h8[8], l8[8];
#pragma unroll
  for (int e = 0; e < 8; ++e) {
    int k = ksg * 16 + kg * 8 + e;
    float v = (k < 2 * WW * DD) ? W1[(size_t)k * HH + j] : 0.f;
    ushort hb = rne_bf16(v);
    h8[e] = hb;
    l8[e] = rne_bf16(v - bf16_to_f(hb));
  }
  size_t o = ((size_t)task * 64 + lane) * 8;
  *reinterpret_cast<uint4*>(fHi + o) = *reinterpret_cast<const uint4*>(h8);
  *reinterpret_cast<uint4*>(fLo + o) = *reinterpret_cast<const uint4*>(l8);
}

// ---------------------------------------------------------------------------
// k2: W2 [256][50000] f32 -> w2t hi/lo [NPAD][256] (linear). 392 blocks.
// Phase1: thread owns n-col (nl=tid&127), reads scalar f32 per k (1KB/row
// wave-coalesced), granule-XOR store to LDS. Phase2: 32 lanes = one n-row's
// 32 granules -> 1KB-contiguous global writes (no write amplification).
// ---------------------------------------------------------------------------
__global__ __launch_bounds__(256, 1)
void k2_w2t(const float* __restrict__ W2, ushort* __restrict__ tHi,
            ushort* __restrict__ tLo) {
  __shared__ ushort Lh[128 * 256];   // 64 KB
  __shared__ ushort Ll[128 * 256];   // 64 KB
  const int tid = threadIdx.x;
  const int nl = tid & 127;
  const int gh = tid >> 7;           // granule half 0/1
  const int n0 = blockIdx.x * 128;
  const int n = n0 + nl;
  for (int q = 0; q < 16; ++q) {
    const int g = gh * 16 + q;       // granule 0..31
    alignas(16) ushort h8[8], l8[8];
#pragma unroll
    for (int e = 0; e < 8; ++e) {
      int k = g * 8 + e;
      float v = (n < VV) ? W2[(size_t)k * VV + n] : 0.f;
      ushort hb = rne_bf16(v);
      h8[e] = hb;
      l8[e] = rne_bf16(v - bf16_to_f(hb));
    }
    const int slot = g ^ (nl & 31);
    *reinterpret_cast<uint4*>(&Lh[nl * 256 + slot * 8]) = *reinterpret_cast<const uint4*>(h8);
    *reinterpret_cast<uint4*>(&Ll[nl * 256 + slot * 8]) = *reinterpret_cast<const uint4*>(l8);
  }
  __syncthreads();
  const int lane = tid & 63;
  const int w = tid >> 6;
  const int g = lane & 31;
  for (int j = 0; j < 16; ++j) {
    int rowl = w * 32 + j * 2 + (lane >> 5);
    int slot = g ^ (rowl & 31);
    uint4 h = *reinterpret_cast<const uint4*>(&Lh[rowl * 256 + slot * 8]);
    uint4 l = *reinterpret_cast<const uint4*>(&Ll[rowl * 256 + slot * 8]);
    size_t o = (size_t)(n0 + rowl) * 256 + g * 8;
    *reinterpret_cast<uint4*>(tHi + o) = h;
    *reinterpret_cast<uint4*>(tLo + o) = l;
  }
}

// ---------------------------------------------------------------------------
// k1: fused gather + GEMM1 + tanh -> h hi/lo [2048][256]. 64 blocks, BM=32.
// K=3072 in 4 chunks of 768 staged in LDS (96KB, granule-XOR). B from
// frag-ordered w1f (contiguous 1KB loads, 1-deep prefetch). No atomics.
// ---------------------------------------------------------------------------
__global__ __launch_bounds__(256, 1)
void k1_gemm1(const int* __restrict__ text, const float* __restrict__ Ef,
              const float* __restrict__ Eu, const ushort* __restrict__ w1fHi,
              const ushort* __restrict__ w1fLo, const float* __restrict__ b1,
              ushort* __restrict__ hHi, ushort* __restrict__ hLo) {
  __shared__ ushort aHi[32 * 768];   // 48 KB
  __shared__ ushort aLo[32 * 768];   // 48 KB
  __shared__ int Toks[32][5];
  const int tid = threadIdx.x;
  const int m0 = blockIdx.x * 32;

  if (tid < 160) {
    int p = tid / 5, w = tid - p * 5;
    int m = m0 + p;
    int t = m >> 4, b = m & 15;
    int tw = t - WW + w;
    Toks[p][w] = (tw >= 0) ? text[tw * 16 + b] : 0;
  }
  __syncthreads();

  const int lane = tid & 63;
  const int wv = tid >> 6;           // wave 0..3 (n-split)
  const int arow = lane & 31;
  const int kg = lane >> 5;
  const int gr = tid >> 3;           // gather row 0..31
  const int lg = tid & 7;

  f32x16 acc[2] = {};

  for (int c = 0; c < 4; ++c) {
    if (c) __syncthreads();
    // ---- gather chunk c: rows 32 x k 768 ----
    for (int ii = 0; ii < 96; ++ii) {
      int kl = ii * 8 + lg;
      int k = c * 768 + kl;
      float v = 0.f;
      if (k < 2 * WW * DD) {
        int wdx = k / (2 * DD);
        int rem = k - wdx * (2 * DD);
        bool upd = rem >= DD;
        int d = upd ? rem - DD : rem;
        const float* tab = upd ? Eu : Ef;
        v = tab[(size_t)Toks[gr][wdx] * DD + d];
      }
      int g = kl >> 3;
      int slot = (g & 96) | ((g & 31) ^ gr);
      int a = gr * 768 + slot * 8 + (kl & 7);
      ushort hb = rne_bf16(v);
      aHi[a] = hb;
      aLo[a] = rne_bf16(v - bf16_to_f(hb));
    }
    __syncthreads();

    // ---- MFMA: 48 ksteps, B 1-deep prefetch ----
    bf16x8 cBH0, cBH1, cBL0, cBL1;
    {
      size_t t0 = ((size_t)((c * 48) * 8 + wv * 2 + 0) * 64 + lane) * 8;
      size_t t1 = ((size_t)((c * 48) * 8 + wv * 2 + 1) * 64 + lane) * 8;
      cBH0 = *reinterpret_cast<const bf16x8*>(w1fHi + t0);
      cBH1 = *reinterpret_cast<const bf16x8*>(w1fHi + t1);
      cBL0 = *reinterpret_cast<const bf16x8*>(w1fLo + t0);
      cBL1 = *reinterpret_cast<const bf16x8*>(w1fLo + t1);
    }
#pragma unroll
    for (int ks = 0; ks < 48; ++ks) {
      bf16x8 nBH0, nBH1, nBL0, nBL1;
      if (ks < 47) {
        size_t t0 = ((size_t)((c * 48 + ks + 1) * 8 + wv * 2 + 0) * 64 + lane) * 8;
        size_t t1 = ((size_t)((c * 48 + ks + 1) * 8 + wv * 2 + 1) * 64 + lane) * 8;
        nBH0 = *reinterpret_cast<const bf16x8*>(w1fHi + t0);
        nBH1 = *reinterpret_cast<const bf16x8*>(w1fHi + t1);
        nBL0 = *reinterpret_cast<const bf16x8*>(w1fLo + t0);
        nBL1 = *reinterpret_cast<const bf16x8*>(w1fLo + t1);
      }
      int g = ks * 2 + kg;
      int slot = (g & 96) | ((g & 31) ^ arow);
      bf16x8 aH = *reinterpret_cast<const bf16x8*>(&aHi[arow * 768 + slot * 8]);
      bf16x8 aL = *reinterpret_cast<const bf16x8*>(&aLo[arow * 768 + slot * 8]);
      acc[0] = __builtin_amdgcn_mfma_f32_32x32x16_bf16(aH, cBH0, acc[0], 0, 0, 0);
      acc[0] = __builtin_amdgcn_mfma_f32_32x32x16_bf16(aH, cBL0, acc[0], 0, 0, 0);
      acc[0] = __builtin_amdgcn_mfma_f32_32x32x16_bf16(aL, cBH0, acc[0], 0, 0, 0);
      acc[1] = __builtin_amdgcn_mfma_f32_32x32x16_bf16(aH, cBH1, acc[1], 0, 0, 0);
      acc[1] = __builtin_amdgcn_mfma_f32_32x32x16_bf16(aH, cBL1, acc[1], 0, 0, 0);
      acc[1] = __builtin_amdgcn_mfma_f32_32x32x16_bf16(aL, cBH1, acc[1], 0, 0, 0);
      if (ks < 47) { cBH0 = nBH0; cBH1 = nBH1; cBL0 = nBL0; cBL1 = nBL1; }
    }
  }

  // ---- epilogue: tanh + hi/lo split, row-major h ----
#pragma unroll
  for (int fn = 0; fn < 2; ++fn) {
    int col = wv * 64 + fn * 32 + arow;
    float bias = b1[col];
#pragma unroll
    for (int rg = 0; rg < 16; ++rg) {
      int row = (rg & 3) + 8 * (rg >> 2) + 4 * kg;
      float th = tanhf(acc[fn][rg] + bias);
      ushort hb = rne_bf16(th);
      hHi[(size_t)(m0 + row) * HH + col] = hb;
      hLo[(size_t)(m0 + row) * HH + col] = rne_bf16(th - bf16_to_f(hb));
    }
  }
}

// ---------------------------------------------------------------------------
// k1f: h [2048][256] hi/lo -> frag-ordered hF: [(mgrp*16+ks)][lane][8].
// Makes kE's A-loads 1KB wave-contiguous. 256 blocks x 4 waves = 1024 tasks.
// ---------------------------------------------------------------------------
__global__ __launch_bounds__(256, 1)
void k1f_frag(const ushort* __restrict__ hHi, const ushort* __restrict__ hLo,
              ushort* __restrict__ fHi, ushort* __restrict__ fLo) {
  const int tid = threadIdx.x;
  const int lane = tid & 63;
  const int task = blockIdx.x * 4 + (tid >> 6);   // mgrp*16 + ks
  const int mgrp = task >> 4, ks = task & 15;
  size_t src = (size_t)(mgrp * 32 + (lane & 31)) * HH + ks * 16 + (lane >> 5) * 8;
  size_t dst = ((size_t)task * 64 + lane) * 8;
  *reinterpret_cast<uint4*>(fHi + dst) = *reinterpret_cast<const uint4*>(hHi + src);
  *reinterpret_cast<uint4*>(fLo + dst) = *reinterpret_cast<const uint4*>(hLo + src);
}

// ---------------------------------------------------------------------------
// kE: logits = h @ W2 + b2, split-bf16 3-term MFMA.
// BM=256 x BN=128, 8 waves (4m x 2n), full K=256 B-tile in 128KB LDS.
// A from frag-ordered hF: contiguous 1KB loads, 4-deep register pipeline.
// B LDS 1-deep prefetch. XCD-grouped grid 3128 (r3-verified bijective).
// ---------------------------------------------------------------------------
__global__ __launch_bounds__(512, 1)
void kE_gemm2(const ushort* __restrict__ hFHi, const ushort* __restrict__ hFLo,
              const ushort* __restrict__ bHiG, const ushort* __restrict__ bLoG,
              const float* __restrict__ b2, float* __restrict__ out) {
  __shared__ ushort Bsh[2][128 * 256];  // 128 KB
  const int tid = threadIdx.x;
  const int lane = tid & 63;
  const int wid = tid >> 6;
  const int wm = wid & 3;
  const int wn = wid >> 2;

  const int bid = blockIdx.x;
  int m_idx, n_idx;
  if (bid < 3072) {
    n_idx = (bid >> 6) * 8 + (bid & 7);
    m_idx = (bid >> 3) & 7;
  } else {
    int local = bid - 3072;
    n_idx = 384 + local % 7;
    m_idx = local / 7;
  }
  const int m0 = m_idx * 256;
  const int n0 = n_idx * 128;

  // ---- stage B hi/lo (XOR-swizzled source granule, linear LDS dest) ----
  {
    const int r = tid >> 5;
    const int p = tid & 31;
    const int wave_off = wid << 10;
    char* baseH = (char*)(&Bsh[0][0]);
    char* baseL = (char*)(&Bsh[1][0]);
#pragma unroll
    for (int i = 0; i < 8; ++i) {
      int row = (i << 4) + r;
      int g = p ^ (row & 31);
      size_t soff = (((size_t)(n0 + row)) << 8) + ((size_t)g << 3);
      __builtin_amdgcn_global_load_lds((as1_u32*)(bHiG + soff),
                                       (as3_u32*)(baseH + (i << 13) + wave_off), 16, 0, 0);
      __builtin_amdgcn_global_load_lds((as1_u32*)(bLoG + soff),
                                       (as3_u32*)(baseL + (i << 13) + wave_off), 16, 0, 0);
    }
  }

  const int arow = lane & 31;
  const int kg = lane >> 5;
  const int mgrp0 = m_idx * 8 + wm * 2;
  const ushort* aH0 = hFHi + ((size_t)(mgrp0 * 16)) * 512 + lane * 8;
  const ushort* aH1 = hFHi + ((size_t)((mgrp0 + 1) * 16)) * 512 + lane * 8;
  const ushort* aL0 = hFLo + ((size_t)(mgrp0 * 16)) * 512 + lane * 8;
  const ushort* aL1 = hFLo + ((size_t)((mgrp0 + 1) * 16)) * 512 + lane * 8;

  // A 4-deep pipeline (compile-time slot indices under full unroll)
  bf16x8 pAH[4][2], pAL[4][2];
#pragma unroll
  for (int s = 0; s < 4; ++s) {
    pAH[s][0] = *reinterpret_cast<const bf16x8*>(aH0 + s * 512);
    pAH[s][1] = *reinterpret_cast<const bf16x8*>(aH1 + s * 512);
    pAL[s][0] = *reinterpret_cast<const bf16x8*>(aL0 + s * 512);
    pAL[s][1] = *reinterpret_cast<const bf16x8*>(aL1 + s * 512);
  }
  __syncthreads();

  const ushort* bHs0 = &Bsh[0][(wn * 64 + 0 * 32 + arow) * 256];
  const ushort* bHs1 = &Bsh[0][(wn * 64 + 1 * 32 + arow) * 256];
  const ushort* bLs0 = &Bsh[1][(wn * 64 + 0 * 32 + arow) * 256];
  const ushort* bLs1 = &Bsh[1][(wn * 64 + 1 * 32 + arow) * 256];

  bf16x8 cBH[2], cBL[2];
  {
    int g0 = ((0 * 2 + kg) ^ arow) * 8;
    cBH[0] = *reinterpret_cast<const bf16x8*>(bHs0 + g0);
    cBH[1] = *reinterpret_cast<const bf16x8*>(bHs1 + g0);
    cBL[0] = *reinterpret_cast<const bf16x8*>(bLs0 + g0);
    cBL[1] = *reinterpret_cast<const bf16x8*>(bLs1 + g0);
  }

  f32x16 acc[2][2] = {};
#pragma unroll
  for (int ks = 0; ks < 16; ++ks) {
    const int s = ks & 3;
    bf16x8 nBH[2], nBL[2];
    if (ks < 15) {
      int g = (((ks + 1) * 2 + kg) ^ arow) * 8;
      nBH[0] = *reinterpret_cast<const bf16x8*>(bHs0 + g);
      nBH[1] = *reinterpret_cast<const bf16x8*>(bHs1 + g);
      nBL[0] = *reinterpret_cast<const bf16x8*>(bLs0 + g);
      nBL[1] = *reinterpret_cast<const bf16x8*>(bLs1 + g);
    }
#pragma unroll
    for (int fm = 0; fm < 2; ++fm)
#pragma unroll
      for (int fn = 0; fn < 2; ++fn) {
        acc[fm][fn] = __builtin_amdgcn_mfma_f32_32x32x16_bf16(pAH[s][fm], cBH[fn], acc[fm][fn], 0, 0, 0);
        acc[fm][fn] = __builtin_amdgcn_mfma_f32_32x32x16_bf16(pAH[s][fm], cBL[fn], acc[fm][fn], 0, 0, 0);
        acc[fm][fn] = __builtin_amdgcn_mfma_f32_32x32x16_bf16(pAL[s][fm], cBH[fn], acc[fm][fn], 0, 0, 0);
      }
    if (ks < 12) {
      pAH[s][0] = *reinterpret_cast<const bf16x8*>(aH0 + (ks + 4) * 512);
      pAH[s][1] = *reinterpret_cast<const bf16x8*>(aH1 + (ks + 4) * 512);
      pAL[s][0] = *reinterpret_cast<const bf16x8*>(aL0 + (ks + 4) * 512);
      pAL[s][1] = *reinterpret_cast<const bf16x8*>(aL1 + (ks + 4) * 512);
    }
    if (ks < 15) { cBH[0] = nBH[0]; cBH[1] = nBH[1]; cBL[0] = nBL[0]; cBL[1] = nBL[1]; }
  }

  // ---- epilogue ----
#pragma unroll
  for (int fn = 0; fn < 2; ++fn) {
    int col = n0 + wn * 64 + fn * 32 + arow;
    bool ok = col < VV;
    float bias = ok ? b2[col] : 0.f;
#pragma unroll
    for (int fm = 0; fm < 2; ++fm) {
      int mbase = m0 + wm * 64 + fm * 32 + 4 * kg;
#pragma unroll
      for (int rg = 0; rg < 16; ++rg) {
        int rr = (rg & 3) + 8 * (rg >> 2);
        if (ok) out[(size_t)(mbase + rr) * VV + col] = acc[fm][fn][rg] + bias;
      }
    }
  }
}

// ---------------------------------------------------------------------------
extern "C" void kernel_launch(void* const* d_in, const int* in_sizes, int n_in,
                              void* d_out, int out_size, void* d_ws, size_t ws_size,
                              hipStream_t stream) {
  (void)in_sizes; (void)n_in; (void)out_size; (void)ws_size;
  const int*   text = (const int*)d_in[0];
  const float* Ef   = (const float*)d_in[1];
  const float* Eu   = (const float*)d_in[2];
  const float* W1   = (const float*)d_in[3];
  const float* b1   = (const float*)d_in[4];
  const float* W2   = (const float*)d_in[5];
  const float* b2   = (const float*)d_in[6];
  float* out = (float*)d_out;

  // workspace (~58.5 MB)
  ushort* w2tHi = (ushort*)d_ws;
  ushort* w2tLo = w2tHi + (size_t)NPAD * 256;
  ushort* w1fHi = w2tLo + (size_t)NPAD * 256;
  ushort* w1fLo = w1fHi + (size_t)KSG1 * 8 * 64 * 8;
  ushort* hHi   = w1fLo + (size_t)KSG1 * 8 * 64 * 8;
  ushort* hLo   = hHi + (size_t)MM * HH;
  ushort* hFHi  = hLo + (size_t)MM * HH;
  ushort* hFLo  = hFHi + (size_t)MM * HH;

  hipLaunchKernelGGL(kW1f, dim3(384), dim3(256), 0, stream, W1, w1fHi, w1fLo);
  hipLaunchKernelGGL(k2_w2t, dim3(NPAD / 128), dim3(256), 0, stream, W2, w2tHi, w2tLo);
  hipLaunchKernelGGL(k1_gemm1, dim3(MM / 32), dim3(256), 0, stream,
                     text, Ef, Eu, w1fHi, w1fLo, b1, hHi, hLo);
  hipLaunchKernelGGL(k1f_frag, dim3(256), dim3(256), 0, stream, hHi, hLo, hFHi, hFLo);
  hipLaunchKernelGGL(kE_gemm2, dim3(3128), dim3(512), 0, stream,
                     hFHi, hFLo, w2tHi, w2tLo, b2, out);
}

// Round 11
// 737.855 us; speedup vs baseline: 1.3850x; 1.2716x over previous
//
#include <hip/hip_runtime.h>
#include <hip/hip_bf16.h>
#include <stdint.h>
#include <stddef.h>

#define VV 50000
#define DD 300
#define HH 256
#define WW 5
#define MM 2048         // T*B
#define NPAD 50176      // 392*128
#define KSG1 192        // GEMM1 k-steps (3072/16)
#define KC1 384         // GEMM1 k-chunk (8 chunks)

typedef __bf16 bf16x8 __attribute__((ext_vector_type(8)));
typedef float  f32x16 __attribute__((ext_vector_type(16)));

typedef const __attribute__((address_space(1))) uint32_t as1_u32;
typedef __attribute__((address_space(3))) uint32_t       as3_u32;

static __device__ __forceinline__ ushort rne_bf16(float v) {
  uint32_t u = __builtin_bit_cast(uint32_t, v);
  u += 0x7fffu + ((u >> 16) & 1u);
  return (ushort)(u >> 16);
}
static __device__ __forceinline__ float bf16_to_f(ushort h) {
  return __builtin_bit_cast(float, (uint32_t)h << 16);
}

// issue a 16B global load via asm so the compiler cannot sink it (T4 pipeline)
#define GLD16(dst, p) \
  asm volatile("global_load_dwordx4 %0, %1, off" \
               : "=&v"(dst) : "v"((unsigned long long)(uintptr_t)(p)))

// ---------------------------------------------------------------------------
// kW1f: W1 [3000][256] f32 -> frag-ordered hi/lo: [(ksg*8+jgrp)][lane][8].
// ---------------------------------------------------------------------------
__global__ __launch_bounds__(256, 1)
void kW1f(const float* __restrict__ W1, ushort* __restrict__ fHi,
          ushort* __restrict__ fLo) {
  const int tid = threadIdx.x;
  const int lane = tid & 63;
  const int task = blockIdx.x * 4 + (tid >> 6);   // 0..1535
  const int ksg = task >> 3;
  const int jgrp = task & 7;
  const int jl = lane & 31, kg = lane >> 5;
  const int j = jgrp * 32 + jl;
  alignas(16) ushort h8[8], l8[8];
#pragma unroll
  for (int e = 0; e < 8; ++e) {
    int k = ksg * 16 + kg * 8 + e;
    float v = (k < 2 * WW * DD) ? W1[(size_t)k * HH + j] : 0.f;
    ushort hb = rne_bf16(v);
    h8[e] = hb;
    l8[e] = rne_bf16(v - bf16_to_f(hb));
  }
  size_t o = ((size_t)task * 64 + lane) * 8;
  *reinterpret_cast<uint4*>(fHi + o) = *reinterpret_cast<const uint4*>(h8);
  *reinterpret_cast<uint4*>(fLo + o) = *reinterpret_cast<const uint4*>(l8);
}

// ---------------------------------------------------------------------------
// k2: W2 [256][50000] f32 -> w2t hi/lo [NPAD][256]. 392 blocks.
// ---------------------------------------------------------------------------
__global__ __launch_bounds__(256, 1)
void k2_w2t(const float* __restrict__ W2, ushort* __restrict__ tHi,
            ushort* __restrict__ tLo) {
  __shared__ ushort Lh[128 * 256];   // 64 KB
  __shared__ ushort Ll[128 * 256];   // 64 KB
  const int tid = threadIdx.x;
  const int nl = tid & 127;
  const int gh = tid >> 7;
  const int n0 = blockIdx.x * 128;
  const int n = n0 + nl;
  for (int q = 0; q < 16; ++q) {
    const int g = gh * 16 + q;
    alignas(16) ushort h8[8], l8[8];
#pragma unroll
    for (int e = 0; e < 8; ++e) {
      int k = g * 8 + e;
      float v = (n < VV) ? W2[(size_t)k * VV + n] : 0.f;
      ushort hb = rne_bf16(v);
      h8[e] = hb;
      l8[e] = rne_bf16(v - bf16_to_f(hb));
    }
    const int slot = g ^ (nl & 31);
    *reinterpret_cast<uint4*>(&Lh[nl * 256 + slot * 8]) = *reinterpret_cast<const uint4*>(h8);
    *reinterpret_cast<uint4*>(&Ll[nl * 256 + slot * 8]) = *reinterpret_cast<const uint4*>(l8);
  }
  __syncthreads();
  const int lane = tid & 63;
  const int w = tid >> 6;
  const int g = lane & 31;
  for (int j = 0; j < 16; ++j) {
    int rowl = w * 32 + j * 2 + (lane >> 5);
    int slot = g ^ (rowl & 31);
    uint4 h = *reinterpret_cast<const uint4*>(&Lh[rowl * 256 + slot * 8]);
    uint4 l = *reinterpret_cast<const uint4*>(&Ll[rowl * 256 + slot * 8]);
    size_t o = (size_t)(n0 + rowl) * 256 + g * 8;
    *reinterpret_cast<uint4*>(tHi + o) = h;
    *reinterpret_cast<uint4*>(tLo + o) = l;
  }
}

// ---------------------------------------------------------------------------
// k1a: GEMM1 split-K partials. Grid 512 = 64 m-blocks x 8 k-chunks (KC1=384).
// Gather chunk into static LDS (float4 loads, token-0 padding), 32x32x16
// MFMA vs frag-ordered w1f, write fp32 partials (no atomics). LDS 48.6KB.
// ---------------------------------------------------------------------------
__global__ __launch_bounds__(256, 1)
void k1a_gemm1(const int* __restrict__ text, const float* __restrict__ Ef,
               const float* __restrict__ Eu, const ushort* __restrict__ w1fHi,
               const ushort* __restrict__ w1fLo, float* __restrict__ parts) {
  __shared__ ushort aHi[32 * KC1];   // 24 KB
  __shared__ ushort aLo[32 * KC1];   // 24 KB
  __shared__ int Toks[32][5];
  const int tid = threadIdx.x;
  const int mblk = blockIdx.x & 63;
  const int kc = blockIdx.x >> 6;
  const int m0 = mblk * 32;
  const int k0 = kc * KC1;

  if (tid < 160) {
    int p = tid / 5, w = tid - p * 5;
    int m = m0 + p;
    int t = m >> 4, b = m & 15;
    int tw = t - WW + w;
    Toks[p][w] = (tw >= 0) ? text[tw * 16 + b] : 0;
  }
  __syncthreads();

  const int G = KC1 >> 3;                 // 48 granules per row
  for (int task = tid; task < 32 * G; task += 256) {
    int row = task & 31;
    int g = task >> 5;
    int k8 = k0 + g * 8;
    float v8[8];
    if (k8 >= 2 * WW * DD) {
#pragma unroll
      for (int e = 0; e < 8; ++e) v8[e] = 0.f;
    } else {
      int wdx = k8 / (2 * DD);
      int rem = k8 - wdx * (2 * DD);
      int tok = Toks[row][wdx];
      const float* ef = Ef + (size_t)tok * DD;
      const float* eu = Eu + (size_t)tok * DD;
      float4 x0, x1;
      if (rem < DD) {
        if (rem <= DD - 8) {
          x0 = *reinterpret_cast<const float4*>(ef + rem);
          x1 = *reinterpret_cast<const float4*>(ef + rem + 4);
        } else {  // rem == 296 straddle
          x0 = *reinterpret_cast<const float4*>(ef + (DD - 4));
          x1 = *reinterpret_cast<const float4*>(eu);
        }
      } else {
        int d = rem - DD;
        x0 = *reinterpret_cast<const float4*>(eu + d);
        x1 = *reinterpret_cast<const float4*>(eu + d + 4);
      }
      v8[0] = x0.x; v8[1] = x0.y; v8[2] = x0.z; v8[3] = x0.w;
      v8[4] = x1.x; v8[5] = x1.y; v8[6] = x1.z; v8[7] = x1.w;
    }
    alignas(16) ushort h8[8], l8[8];
#pragma unroll
    for (int e = 0; e < 8; ++e) {
      ushort hb = rne_bf16(v8[e]);
      h8[e] = hb;
      l8[e] = rne_bf16(v8[e] - bf16_to_f(hb));
    }
    int gb = g & ~31;
    int slot = (gb == 0) ? (gb | ((g & 31) ^ (row & 31)))     // block of 32
                         : (gb | ((g & 15) ^ (row & 15)));    // tail block of 16
    *reinterpret_cast<uint4*>(&aHi[row * KC1 + slot * 8]) = *reinterpret_cast<const uint4*>(h8);
    *reinterpret_cast<uint4*>(&aLo[row * KC1 + slot * 8]) = *reinterpret_cast<const uint4*>(l8);
  }
  __syncthreads();

  const int lane = tid & 63;
  const int wv = tid >> 6;                // n-group 0..3
  const int arow = lane & 31;
  const int kg = lane >> 5;
  const int gs0 = k0 >> 4;                // global kstep base

  f32x16 acc[2] = {};
  for (int ks = 0; ks < KC1 / 16; ++ks) {
    int g = ks * 2 + kg;
    int gb = g & ~31;
    int slot = (gb == 0) ? (gb | ((g & 31) ^ arow))
                         : (gb | ((g & 15) ^ (arow & 15)));
    bf16x8 aH = *reinterpret_cast<const bf16x8*>(&aHi[arow * KC1 + slot * 8]);
    bf16x8 aL = *reinterpret_cast<const bf16x8*>(&aLo[arow * KC1 + slot * 8]);
#pragma unroll
    for (int fn = 0; fn < 2; ++fn) {
      size_t bo = (((size_t)(gs0 + ks) * 8 + wv * 2 + fn) * 64 + lane) * 8;
      bf16x8 bH = *reinterpret_cast<const bf16x8*>(w1fHi + bo);
      bf16x8 bL = *reinterpret_cast<const bf16x8*>(w1fLo + bo);
      acc[fn] = __builtin_amdgcn_mfma_f32_32x32x16_bf16(aH, bH, acc[fn], 0, 0, 0);
      acc[fn] = __builtin_amdgcn_mfma_f32_32x32x16_bf16(aH, bL, acc[fn], 0, 0, 0);
      acc[fn] = __builtin_amdgcn_mfma_f32_32x32x16_bf16(aL, bH, acc[fn], 0, 0, 0);
    }
  }

  float* pbase = parts + ((size_t)kc * MM + m0) * HH;
#pragma unroll
  for (int fn = 0; fn < 2; ++fn) {
    int col = wv * 64 + fn * 32 + arow;
#pragma unroll
    for (int rg = 0; rg < 16; ++rg) {
      int row = (rg & 3) + 8 * (rg >> 2) + 4 * kg;
      pbase[row * HH + col] = acc[fn][rg];
    }
  }
}

// ---------------------------------------------------------------------------
// k1c: sum 8 partials + b1, tanh, split hi/lo, write hF frag-order. 256 blk.
// ---------------------------------------------------------------------------
__global__ __launch_bounds__(256, 1)
void k1c_act(const float* __restrict__ parts, const float* __restrict__ b1,
             ushort* __restrict__ fHi, ushort* __restrict__ fLo) {
  int gid = blockIdx.x * 256 + threadIdx.x;   // 65536
  int m = gid >> 5, jg = gid & 31;
  float4 sa = *reinterpret_cast<const float4*>(b1 + jg * 8);
  float4 sb = *reinterpret_cast<const float4*>(b1 + jg * 8 + 4);
  for (int p = 0; p < 8; ++p) {
    const float* q = parts + ((size_t)p * MM + m) * HH + jg * 8;
    float4 a = *reinterpret_cast<const float4*>(q);
    float4 b = *reinterpret_cast<const float4*>(q + 4);
    sa.x += a.x; sa.y += a.y; sa.z += a.z; sa.w += a.w;
    sb.x += b.x; sb.y += b.y; sb.z += b.z; sb.w += b.w;
  }
  float t8[8] = {tanhf(sa.x), tanhf(sa.y), tanhf(sa.z), tanhf(sa.w),
                 tanhf(sb.x), tanhf(sb.y), tanhf(sb.z), tanhf(sb.w)};
  alignas(16) ushort h8[8], l8[8];
#pragma unroll
  for (int e = 0; e < 8; ++e) {
    ushort hb = rne_bf16(t8[e]);
    h8[e] = hb;
    l8[e] = rne_bf16(t8[e] - bf16_to_f(hb));
  }
  size_t dst = (((size_t)(m >> 5) * 16 + (jg >> 1)) * 64 + (jg & 1) * 32 + (m & 31)) * 8;
  *reinterpret_cast<uint4*>(fHi + dst) = *reinterpret_cast<const uint4*>(h8);
  *reinterpret_cast<uint4*>(fLo + dst) = *reinterpret_cast<const uint4*>(l8);
}

// ---------------------------------------------------------------------------
// Fallback GEMM1 (r5-proven monolithic) + relayout.
// ---------------------------------------------------------------------------
__global__ __launch_bounds__(256, 1)
void k1_gemm1(const int* __restrict__ text, const float* __restrict__ Ef,
              const float* __restrict__ Eu, const ushort* __restrict__ w1fHi,
              const ushort* __restrict__ w1fLo, const float* __restrict__ b1,
              ushort* __restrict__ hHi, ushort* __restrict__ hLo) {
  __shared__ ushort aHi[32 * 768];
  __shared__ ushort aLo[32 * 768];
  __shared__ int Toks[32][5];
  const int tid = threadIdx.x;
  const int m0 = blockIdx.x * 32;
  if (tid < 160) {
    int p = tid / 5, w = tid - p * 5;
    int m = m0 + p;
    int t = m >> 4, b = m & 15;
    int tw = t - WW + w;
    Toks[p][w] = (tw >= 0) ? text[tw * 16 + b] : 0;
  }
  __syncthreads();
  const int lane = tid & 63;
  const int wv = tid >> 6;
  const int arow = lane & 31;
  const int kg = lane >> 5;
  const int gr = tid >> 3;
  const int lg = tid & 7;
  f32x16 acc[2] = {};
  for (int c = 0; c < 4; ++c) {
    if (c) __syncthreads();
    for (int ii = 0; ii < 96; ++ii) {
      int kl = ii * 8 + lg;
      int k = c * 768 + kl;
      float v = 0.f;
      if (k < 2 * WW * DD) {
        int wdx = k / (2 * DD);
        int rem = k - wdx * (2 * DD);
        bool upd = rem >= DD;
        int d = upd ? rem - DD : rem;
        const float* tab = upd ? Eu : Ef;
        v = tab[(size_t)Toks[gr][wdx] * DD + d];
      }
      int g = kl >> 3;
      int slot = (g & 96) | ((g & 31) ^ gr);
      int a = gr * 768 + slot * 8 + (kl & 7);
      ushort hb = rne_bf16(v);
      aHi[a] = hb;
      aLo[a] = rne_bf16(v - bf16_to_f(hb));
    }
    __syncthreads();
    for (int ks = 0; ks < 48; ++ks) {
      int g = ks * 2 + kg;
      int slot = (g & 96) | ((g & 31) ^ arow);
      bf16x8 aH = *reinterpret_cast<const bf16x8*>(&aHi[arow * 768 + slot * 8]);
      bf16x8 aL = *reinterpret_cast<const bf16x8*>(&aLo[arow * 768 + slot * 8]);
#pragma unroll
      for (int fn = 0; fn < 2; ++fn) {
        size_t bo = (((size_t)(c * 48 + ks) * 8 + wv * 2 + fn) * 64 + lane) * 8;
        bf16x8 bH = *reinterpret_cast<const bf16x8*>(w1fHi + bo);
        bf16x8 bL = *reinterpret_cast<const bf16x8*>(w1fLo + bo);
        acc[fn] = __builtin_amdgcn_mfma_f32_32x32x16_bf16(aH, bH, acc[fn], 0, 0, 0);
        acc[fn] = __builtin_amdgcn_mfma_f32_32x32x16_bf16(aH, bL, acc[fn], 0, 0, 0);
        acc[fn] = __builtin_amdgcn_mfma_f32_32x32x16_bf16(aL, bH, acc[fn], 0, 0, 0);
      }
    }
  }
#pragma unroll
  for (int fn = 0; fn < 2; ++fn) {
    int col = wv * 64 + fn * 32 + arow;
    float bias = b1[col];
#pragma unroll
    for (int rg = 0; rg < 16; ++rg) {
      int row = (rg & 3) + 8 * (rg >> 2) + 4 * kg;
      float th = tanhf(acc[fn][rg] + bias);
      ushort hb = rne_bf16(th);
      hHi[(size_t)(m0 + row) * HH + col] = hb;
      hLo[(size_t)(m0 + row) * HH + col] = rne_bf16(th - bf16_to_f(hb));
    }
  }
}

__global__ __launch_bounds__(256, 1)
void k1f_frag(const ushort* __restrict__ hHi, const ushort* __restrict__ hLo,
              ushort* __restrict__ fHi, ushort* __restrict__ fLo) {
  const int tid = threadIdx.x;
  const int lane = tid & 63;
  const int task = blockIdx.x * 4 + (tid >> 6);
  const int mgrp = task >> 4, ks = task & 15;
  size_t src = (size_t)(mgrp * 32 + (lane & 31)) * HH + ks * 16 + (lane >> 5) * 8;
  size_t dst = ((size_t)task * 64 + lane) * 8;
  *reinterpret_cast<uint4*>(fHi + dst) = *reinterpret_cast<const uint4*>(hHi + src);
  *reinterpret_cast<uint4*>(fLo + dst) = *reinterpret_cast<const uint4*>(hLo + src);
}

// ---------------------------------------------------------------------------
// kE: logits = h @ W2 + b2. BM=256 x BN=128, 8 waves, K=256 B-tile in LDS.
// A-loads forced 3-ksteps ahead via asm + counted vmcnt (T4). XCD grouping.
// ---------------------------------------------------------------------------
__global__ __launch_bounds__(512, 1)
void kE_gemm2(const ushort* __restrict__ hFHi, const ushort* __restrict__ hFLo,
              const ushort* __restrict__ bHiG, const ushort* __restrict__ bLoG,
              const float* __restrict__ b2, float* __restrict__ out) {
  __shared__ ushort Bsh[2][128 * 256];  // 128 KB
  const int tid = threadIdx.x;
  const int lane = tid & 63;
  const int wid = tid >> 6;
  const int wm = wid & 3;
  const int wn = wid >> 2;

  const int bid = blockIdx.x;
  int m_idx, n_idx;
  if (bid < 3072) {
    n_idx = (bid >> 6) * 8 + (bid & 7);
    m_idx = (bid >> 3) & 7;
  } else {
    int local = bid - 3072;
    n_idx = 384 + local % 7;
    m_idx = local / 7;
  }
  const int m0 = m_idx * 256;
  const int n0 = n_idx * 128;

  {  // stage B hi/lo (XOR-swizzled source granule, linear LDS dest)
    const int r = tid >> 5;
    const int p = tid & 31;
    const int wave_off = wid << 10;
    char* baseH = (char*)(&Bsh[0][0]);
    char* baseL = (char*)(&Bsh[1][0]);
#pragma unroll
    for (int i = 0; i < 8; ++i) {
      int row = (i << 4) + r;
      int g = p ^ (row & 31);
      size_t soff = (((size_t)(n0 + row)) << 8) + ((size_t)g << 3);
      __builtin_amdgcn_global_load_lds((as1_u32*)(bHiG + soff),
                                       (as3_u32*)(baseH + (i << 13) + wave_off), 16, 0, 0);
      __builtin_amdgcn_global_load_lds((as1_u32*)(bLoG + soff),
                                       (as3_u32*)(baseL + (i << 13) + wave_off), 16, 0, 0);
    }
  }

  const int arow = lane & 31;
  const int kg = lane >> 5;
  const int mgrp0 = m_idx * 8 + wm * 2;
  const ushort* aH0 = hFHi + ((size_t)(mgrp0 * 16)) * 512 + lane * 8;
  const ushort* aH1 = hFHi + ((size_t)((mgrp0 + 1) * 16)) * 512 + lane * 8;
  const ushort* aL0 = hFLo + ((size_t)(mgrp0 * 16)) * 512 + lane * 8;
  const ushort* aL1 = hFLo + ((size_t)((mgrp0 + 1) * 16)) * 512 + lane * 8;

  uint4 pH0[4], pH1[4], pL0[4], pL1[4];
#pragma unroll
  for (int s = 0; s < 3; ++s) {      // prologue ks=0..2
    GLD16(pH0[s], aH0 + s * 512);
    GLD16(pH1[s], aH1 + s * 512);
    GLD16(pL0[s], aL0 + s * 512);
    GLD16(pL1[s], aL1 + s * 512);
  }
  __syncthreads();

  const ushort* bHs0 = &Bsh[0][(wn * 64 + 0 * 32 + arow) * 256];
  const ushort* bHs1 = &Bsh[0][(wn * 64 + 1 * 32 + arow) * 256];
  const ushort* bLs0 = &Bsh[1][(wn * 64 + 0 * 32 + arow) * 256];
  const ushort* bLs1 = &Bsh[1][(wn * 64 + 1 * 32 + arow) * 256];

  bf16x8 cBH[2], cBL[2];
  {
    int g0 = (kg ^ arow) * 8;
    cBH[0] = *reinterpret_cast<const bf16x8*>(bHs0 + g0);
    cBH[1] = *reinterpret_cast<const bf16x8*>(bHs1 + g0);
    cBL[0] = *reinterpret_cast<const bf16x8*>(bLs0 + g0);
    cBL[1] = *reinterpret_cast<const bf16x8*>(bLs1 + g0);
  }

  f32x16 acc[2][2] = {};
#pragma unroll
  for (int ks = 0; ks < 16; ++ks) {
    const int s = ks & 3;
    if (ks + 3 < 16) {               // issue A for ks+3
      const int t = (ks + 3) & 3;
      GLD16(pH0[t], aH0 + (ks + 3) * 512);
      GLD16(pH1[t], aH1 + (ks + 3) * 512);
      GLD16(pL0[t], aL0 + (ks + 3) * 512);
      GLD16(pL1[t], aL1 + (ks + 3) * 512);
    }
    bf16x8 nBH[2], nBL[2];
    if (ks < 15) {
      int g = (((ks + 1) * 2 + kg) ^ arow) * 8;
      nBH[0] = *reinterpret_cast<const bf16x8*>(bHs0 + g);
      nBH[1] = *reinterpret_cast<const bf16x8*>(bHs1 + g);
      nBL[0] = *reinterpret_cast<const bf16x8*>(bLs0 + g);
      nBL[1] = *reinterpret_cast<const bf16x8*>(bLs1 + g);
    }
    if (ks < 13)       asm volatile("s_waitcnt vmcnt(12)");
    else if (ks == 13) asm volatile("s_waitcnt vmcnt(8)");
    else if (ks == 14) asm volatile("s_waitcnt vmcnt(4)");
    else               asm volatile("s_waitcnt vmcnt(0)");
    __builtin_amdgcn_sched_barrier(0);
    bf16x8 aHf[2] = {__builtin_bit_cast(bf16x8, pH0[s]), __builtin_bit_cast(bf16x8, pH1[s])};
    bf16x8 aLf[2] = {__builtin_bit_cast(bf16x8, pL0[s]), __builtin_bit_cast(bf16x8, pL1[s])};
#pragma unroll
    for (int fm = 0; fm < 2; ++fm)
#pragma unroll
      for (int fn = 0; fn < 2; ++fn) {
        acc[fm][fn] = __builtin_amdgcn_mfma_f32_32x32x16_bf16(aHf[fm], cBH[fn], acc[fm][fn], 0, 0, 0);
        acc[fm][fn] = __builtin_amdgcn_mfma_f32_32x32x16_bf16(aHf[fm], cBL[fn], acc[fm][fn], 0, 0, 0);
        acc[fm][fn] = __builtin_amdgcn_mfma_f32_32x32x16_bf16(aLf[fm], cBH[fn], acc[fm][fn], 0, 0, 0);
      }
    if (ks < 15) { cBH[0] = nBH[0]; cBH[1] = nBH[1]; cBL[0] = nBL[0]; cBL[1] = nBL[1]; }
  }

#pragma unroll
  for (int fn = 0; fn < 2; ++fn) {
    int col = n0 + wn * 64 + fn * 32 + arow;
    bool ok = col < VV;
    float bias = ok ? b2[col] : 0.f;
#pragma unroll
    for (int fm = 0; fm < 2; ++fm) {
      int mbase = m0 + wm * 64 + fm * 32 + 4 * kg;
#pragma unroll
      for (int rg = 0; rg < 16; ++rg) {
        int rr = (rg & 3) + 8 * (rg >> 2);
        if (ok) out[(size_t)(mbase + rr) * VV + col] = acc[fm][fn][rg] + bias;
      }
    }
  }
}

// ---------------------------------------------------------------------------
extern "C" void kernel_launch(void* const* d_in, const int* in_sizes, int n_in,
                              void* d_out, int out_size, void* d_ws, size_t ws_size,
                              hipStream_t stream) {
  (void)in_sizes; (void)n_in; (void)out_size;
  const int*   text = (const int*)d_in[0];
  const float* Ef   = (const float*)d_in[1];
  const float* Eu   = (const float*)d_in[2];
  const float* W1   = (const float*)d_in[3];
  const float* b1   = (const float*)d_in[4];
  const float* W2   = (const float*)d_in[5];
  const float* b2   = (const float*)d_in[6];
  float* out = (float*)d_out;

  // layout: [w2t hi|lo 51.38MB][w1f hi|lo 3.15MB][parts or htmp]
  // hF aliases the (dead-after-GEMM1) w1f region.
  ushort* w2tHi = (ushort*)d_ws;
  ushort* w2tLo = w2tHi + (size_t)NPAD * 256;
  ushort* w1fHi = w2tLo + (size_t)NPAD * 256;
  ushort* w1fLo = w1fHi + (size_t)KSG1 * 8 * 64 * 8;   // 786432 shorts
  char*   after = (char*)(w1fLo + (size_t)KSG1 * 8 * 64 * 8);
  ushort* hFHi  = w1fHi;                                // alias (2.1MB < 3.15MB)
  ushort* hFLo  = w1fHi + (size_t)MM * HH;

  const size_t baseB = (size_t)NPAD * 256 * 2 * 2 + (size_t)KSG1 * 8 * 64 * 8 * 2 * 2;
  const size_t partB = (size_t)MM * HH * 4;            // 2MB per chunk

  hipLaunchKernelGGL(kW1f, dim3(384), dim3(256), 0, stream, W1, w1fHi, w1fLo);
  hipLaunchKernelGGL(k2_w2t, dim3(NPAD / 128), dim3(256), 0, stream, W2, w2tHi, w2tLo);

  if (ws_size >= baseB + 8 * partB) {          // 71.3MB: fast path, 8 k-chunks
    float* parts = (float*)after;
    hipLaunchKernelGGL(k1a_gemm1, dim3(64 * 8), dim3(256), 0, stream,
                       text, Ef, Eu, w1fHi, w1fLo, parts);
    hipLaunchKernelGGL(k1c_act, dim3(256), dim3(256), 0, stream, parts, b1, hFHi, hFLo);
  } else {                                     // 56.6MB fallback (r5-proven path)
    ushort* hHi = (ushort*)after;
    ushort* hLo = hHi + (size_t)MM * HH;
    hipLaunchKernelGGL(k1_gemm1, dim3(MM / 32), dim3(256), 0, stream,
                       text, Ef, Eu, w1fHi, w1fLo, b1, hHi, hLo);
    hipLaunchKernelGGL(k1f_frag, dim3(256), dim3(256), 0, stream, hHi, hLo, hFHi, hFLo);
  }

  hipLaunchKernelGGL(kE_gemm2, dim3(3128), dim3(512), 0, stream,
                     hFHi, hFLo, w2tHi, w2tLo, b2, out);
}